// Round 18
// baseline (198.781 us; speedup 1.0000x reference)
//
#include <hip/hip_runtime.h>

typedef _Float16 f16;
typedef _Float16 f16x8 __attribute__((ext_vector_type(8)));
typedef _Float16 f16x4 __attribute__((ext_vector_type(4)));
typedef float   f32x4 __attribute__((ext_vector_type(4)));

#define LOG2E 1.44269504088896340736f

__device__ __forceinline__ f32x4 mfma_f16(f16x8 a, f16x8 b, f32x4 c){
  return __builtin_amdgcn_mfma_f32_16x16x32_f16(a, b, c, 0, 0, 0);
}
__device__ __forceinline__ float fexp2(float x){ return __builtin_amdgcn_exp2f(x); }

// global -> LDS direct DMA, 16B per lane. lds must be wave-uniform base;
// HW writes base + lane*16. Source address is per-lane (pre-swizzled).
__device__ __forceinline__ void gld16(void* lds, const void* g){
  __builtin_amdgcn_global_load_lds(
      (const __attribute__((address_space(1))) unsigned int*)g,
      (__attribute__((address_space(3))) unsigned int*)lds,
      16, 0, 0);
}

// BK=64 swizzle (128B rows): pos ^ (row&7); staging XOR (l&7)^(l>>3).
// BK=32 swizzle (64B rows):  pos ^ ((row>>1)&3); staging XOR (l&3)^((l>>3)&3).
// Both validated r9-r17 (0 conflicts).
// LESSONS: (r12) launch_bounds min-waves too high -> VGPR cap -> spill.
//          (r15) dbuf at REDUCED occupancy loses; (r17 move) dbuf at EQUAL
//          occupancy via BK=32 is the remaining schedule lever.
//          (r16) setprio = null on this pipeline.

// ---------------------------------------------------------------------------
// k_prep_g: B16[n][e] = sum_x Wk[n][x]*Wq[e][x]  (= (Wq Wk^T)^T), n<512.
// ---------------------------------------------------------------------------
__global__ __launch_bounds__(256) void k_prep_g(const float* __restrict__ Wq,
                                                const float* __restrict__ Wk,
                                                f16* __restrict__ B16){
  __shared__ float ak[32][36];
  __shared__ float aq[32][36];
  const int n0 = blockIdx.y * 32, e0 = blockIdx.x * 32;
  const int u = threadIdx.x;
  const int ty = u >> 4, tx = u & 15;
  float acc[2][2] = {};
  for (int x0 = 0; x0 < 512; x0 += 32){
    __syncthreads();
    {
      int r = u >> 3, c4 = (u & 7) * 4;
      *(float4*)&ak[r][c4] = *(const float4*)&Wk[(n0 + r) * 512 + x0 + c4];
      *(float4*)&aq[r][c4] = *(const float4*)&Wq[(e0 + r) * 512 + x0 + c4];
    }
    __syncthreads();
#pragma unroll 8
    for (int x = 0; x < 32; ++x){
      float k0 = ak[ty * 2 + 0][x], k1 = ak[ty * 2 + 1][x];
      float q0 = aq[tx * 2 + 0][x], q1 = aq[tx * 2 + 1][x];
      acc[0][0] += k0 * q0; acc[0][1] += k0 * q1;
      acc[1][0] += k1 * q0; acc[1][1] += k1 * q1;
    }
  }
#pragma unroll
  for (int i = 0; i < 2; ++i)
#pragma unroll
    for (int j = 0; j < 2; ++j)
      B16[(size_t)(n0 + ty * 2 + i) * 512 + e0 + tx * 2 + j] = (f16)acc[i][j];
}

// ---------------------------------------------------------------------------
// k_prep_wv: B16[512+d][e] = Wv[e][d]  (transpose + fp16 cast)
// ---------------------------------------------------------------------------
__global__ __launch_bounds__(256) void k_prep_wv(const float* __restrict__ Wv,
                                                 f16* __restrict__ B16){
  __shared__ float t[64][72];
  const int e0 = blockIdx.x * 64, h0 = blockIdx.y * 64;
  const int u = threadIdx.x;
#pragma unroll
  for (int k = 0; k < 4; ++k){
    int idx = u + k * 256; int r = idx >> 4, c4 = (idx & 15) * 4;
    *(float4*)&t[r][c4] = *(const float4*)&Wv[(e0 + r) * 512 + h0 + c4];
  }
  __syncthreads();
#pragma unroll
  for (int k = 0; k < 4; ++k){
    int idx = u + k * 256; int j = idx >> 4, i4 = (idx & 15) * 4;
#pragma unroll
    for (int c = 0; c < 4; ++c)
      B16[(size_t)(512 + h0 + j) * 512 + e0 + i4 + c] = (f16)t[i4 + c][j];
  }
}

// ---------------------------------------------------------------------------
// k_cast: tokens fp32 -> fp16, 8/thread.
// ---------------------------------------------------------------------------
__global__ __launch_bounds__(256) void k_cast(const float* __restrict__ tok,
                                              f16* __restrict__ T16){
  int i = blockIdx.x * 256 + threadIdx.x;
  const float4* p = (const float4*)tok + (size_t)i * 2;
  float4 a = p[0], b = p[1];
  f16x8 h;
  h[0] = (f16)a.x; h[1] = (f16)a.y; h[2] = (f16)a.z; h[3] = (f16)a.w;
  h[4] = (f16)b.x; h[5] = (f16)b.y; h[6] = (f16)b.z; h[7] = (f16)b.w;
  *((f16x8*)T16 + i) = h;
}

// ---------------------------------------------------------------------------
// k_gemm: C[t][n] = sum_e T16[t][e]*B16[n][e]; n<512 -> QG[t][n],
// n>=512 -> VT[b][d][s]. 128x128 tile, BK=64 single-buffered, 32KB LDS ->
// 4 blocks/CU (r14-validated).
// ---------------------------------------------------------------------------
__global__ __launch_bounds__(256, 4) void k_gemm(const f16* __restrict__ T16,
                                                 const f16* __restrict__ B16,
                                                 f16* __restrict__ QG,
                                                 f16* __restrict__ VT){
  __shared__ __align__(16) f16 Abuf[128 * 64];  // 16KB
  __shared__ __align__(16) f16 Bbuf[128 * 64];  // 16KB
  const int tb = blockIdx.x, nb = blockIdx.y;
  const int u = threadIdx.x;
  const int w = u >> 6, l = u & 63, lr = l & 15, lq = l >> 4;
  const int sx8 = (l & 7) ^ (l >> 3), hi8 = l >> 3;
  const int wm = (w & 1) * 64, wn = (w >> 1) * 64;
  f32x4 acc[4][4] = {};
  const f16* sa0 = T16 + (size_t)tb * 128 * 512;
  const f16* sb0 = B16 + (size_t)nb * 128 * 512;
  for (int c = 0; c < 8; ++c){
    {
      const f16* sa = sa0 + c * 64;
      const f16* sb_ = sb0 + c * 64;
#pragma unroll
      for (int k = 0; k < 4; ++k){
        int i = w * 4 + k;
        int row = i * 8 + hi8;
        gld16((char*)Abuf + i * 1024, sa  + (size_t)row * 512 + sx8 * 8);
        gld16((char*)Bbuf + i * 1024, sb_ + (size_t)row * 512 + sx8 * 8);
      }
    }
    __syncthreads();
#pragma unroll
    for (int es = 0; es < 2; ++es){
      f16x8 af[4], bf[4];
#pragma unroll
      for (int mt = 0; mt < 4; ++mt){
        int row = wm + mt * 16 + lr;
        af[mt] = *(const f16x8*)((const char*)Abuf + row * 128 + (((es * 4 + lq) ^ (row & 7)) << 4));
      }
#pragma unroll
      for (int nt = 0; nt < 4; ++nt){
        int row = wn + nt * 16 + lr;
        bf[nt] = *(const f16x8*)((const char*)Bbuf + row * 128 + (((es * 4 + lq) ^ (row & 7)) << 4));
      }
#pragma unroll
      for (int mt = 0; mt < 4; ++mt)
#pragma unroll
        for (int nt = 0; nt < 4; ++nt)
          acc[mt][nt] = mfma_f16(af[mt], bf[nt], acc[mt][nt]);
    }
    __syncthreads();
  }
  if (nb < 4){
#pragma unroll
    for (int mt = 0; mt < 4; ++mt)
#pragma unroll
      for (int nt = 0; nt < 4; ++nt){
        int n = nb * 128 + wn + nt * 16 + lr;
        int r0 = tb * 128 + wm + mt * 16 + lq * 4;
#pragma unroll
        for (int j = 0; j < 4; ++j)
          QG[(size_t)(r0 + j) * 512 + n] = (f16)acc[mt][nt][j];
      }
  } else {
#pragma unroll
    for (int mt = 0; mt < 4; ++mt)
#pragma unroll
      for (int nt = 0; nt < 4; ++nt){
        int h = (nb - 4) * 128 + wn + nt * 16 + lr;
        int r0 = tb * 128 + wm + mt * 16 + lq * 4;
        int bq = r0 >> 11, s = r0 & 2047;
        f16x4 hv;
#pragma unroll
        for (int j = 0; j < 4; ++j) hv[j] = (f16)acc[mt][nt][j];
        *(f16x4*)&VT[(size_t)(bq * 512 + h) * 2048 + s] = hv;
      }
  }
}

// ---------------------------------------------------------------------------
// k_pass1p: S-GEMM 128s x 256t tile, 512 threads (8 waves, wave 64x64),
// BK=32 DOUBLE-buffered, 1 barrier/chunk (stage(c+1) overlaps compute(c)).
// LDS 2*(8+16)KB + 4KB red = 52KB -> 3 blocks/CU — SAME occupancy as r14's
// single-buf BK=64, strictly more overlap. 16 chunks x 16 MFMA/wave.
// Block = (b, sb 16, tb 8), grid 1024.
// ---------------------------------------------------------------------------
__global__ __launch_bounds__(512, 2) void k_pass1p(const f16* __restrict__ T16,
                                                   const f16* __restrict__ QG,
                                                   f16* __restrict__ Pp,
                                                   float* __restrict__ Mp,
                                                   float* __restrict__ Dp){
  const int gid = blockIdx.x;
  const int b = gid & 7;
  const int sb = (gid >> 3) & 15;
  const int tb = gid >> 7;              // 0..7, 256-wide t tiles
  const int u = threadIdx.x;
  const int w = u >> 6, l = u & 63, lr = l & 15, lq = l >> 4;
  const int sx4 = (l & 3) ^ ((l >> 3) & 3), hi4 = l >> 2;
  const int ws2 = w & 1, wt2 = w >> 1;  // s half, t quarter
  const int wm = ws2 * 64, wn = wt2 * 64;

  __shared__ __align__(16) f16 Abuf[2][128 * 32];  // T16 s-rows, 2*8KB
  __shared__ __align__(16) f16 Bbuf[2][256 * 32];  // QG  t-rows, 2*16KB
  __shared__ float redM[4][128];
  __shared__ float redD[4][128];

  f32x4 acc[4][4] = {};
  const f16* sa0 = T16 + ((size_t)(b * 2048 + sb * 128) * 512);
  const f16* sb0 = QG + ((size_t)(b * 2048 + tb * 256) * 512);
  auto stage = [&](int c, int buf){
    const f16* sa = sa0 + c * 32;
    const f16* sb_ = sb0 + c * 32;
    { // A: 8 slots of 1KB, 1 per wave (rows w*16+hi4)
      int row = w * 16 + hi4;
      gld16((char*)&Abuf[buf][0] + w * 1024, sa + (size_t)row * 512 + sx4 * 8);
    }
#pragma unroll
    for (int k = 0; k < 2; ++k){ // B: 16 slots, 2 per wave
      int i = w * 2 + k;
      int row = i * 16 + hi4;
      gld16((char*)&Bbuf[buf][0] + i * 1024, sb_ + (size_t)row * 512 + sx4 * 8);
    }
  };
  stage(0, 0);
  for (int c = 0; c < 16; ++c){
    __syncthreads();   // stage(c) landed; prior reads of buf[(c+1)&1] done
    if (c < 15) stage(c + 1, (c + 1) & 1);
    const f16* A = &Abuf[c & 1][0];
    const f16* B = &Bbuf[c & 1][0];
    f16x8 af[4], bf[4];
#pragma unroll
    for (int mt = 0; mt < 4; ++mt){
      int row = wm + mt * 16 + lr;
      af[mt] = *(const f16x8*)((const char*)A + row * 64 + ((lq ^ ((row >> 1) & 3)) << 4));
    }
#pragma unroll
    for (int nt = 0; nt < 4; ++nt){
      int row = wn + nt * 16 + lr;
      bf[nt] = *(const f16x8*)((const char*)B + row * 64 + ((lq ^ ((row >> 1) & 3)) << 4));
    }
#pragma unroll
    for (int mt = 0; mt < 4; ++mt)
#pragma unroll
      for (int nt = 0; nt < 4; ++nt)
        acc[mt][nt] = mfma_f16(af[mt], bf[nt], acc[mt][nt]);
  }
  // ---- epilogue: x = S*log2e; col max over the block's 256 t ----
#pragma unroll
  for (int mt = 0; mt < 4; ++mt)
#pragma unroll
    for (int nt = 0; nt < 4; ++nt)
#pragma unroll
      for (int j = 0; j < 4; ++j)
        acc[mt][nt][j] *= LOG2E;
#pragma unroll
  for (int mt = 0; mt < 4; ++mt)
#pragma unroll
    for (int j = 0; j < 4; ++j){
      float m2 = fmaxf(fmaxf(acc[mt][0][j], acc[mt][1][j]),
                       fmaxf(acc[mt][2][j], acc[mt][3][j]));
#pragma unroll
      for (int off = 1; off <= 8; off <<= 1)
        m2 = fmaxf(m2, __shfl_xor(m2, off, 64));
      if (lr == 0) redM[wt2][wm + mt * 16 + lq * 4 + j] = m2;
    }
  __syncthreads();
  float M[4][4];
#pragma unroll
  for (int mt = 0; mt < 4; ++mt)
#pragma unroll
    for (int j = 0; j < 4; ++j){
      int idx = wm + mt * 16 + lq * 4 + j;
      M[mt][j] = fmaxf(fmaxf(redM[0][idx], redM[1][idx]),
                       fmaxf(redM[2][idx], redM[3][idx]));
    }
  // ---- P' = exp2(x - M), store fp16, col sums ----
#pragma unroll
  for (int mt = 0; mt < 4; ++mt)
#pragma unroll
    for (int nt = 0; nt < 4; ++nt){
      int t = tb * 256 + wn + nt * 16 + lr;
      f16x4 h4;
#pragma unroll
      for (int j = 0; j < 4; ++j){
        float p = fexp2(acc[mt][nt][j] - M[mt][j]);
        acc[mt][nt][j] = p;
        h4[j] = (f16)p;
      }
      *(f16x4*)&Pp[(size_t)(b * 2048 + t) * 2048 + sb * 128 + wm + mt * 16 + lq * 4] = h4;
    }
#pragma unroll
  for (int mt = 0; mt < 4; ++mt)
#pragma unroll
    for (int j = 0; j < 4; ++j){
      float sd = acc[mt][0][j] + acc[mt][1][j] + acc[mt][2][j] + acc[mt][3][j];
#pragma unroll
      for (int off = 1; off <= 8; off <<= 1)
        sd += __shfl_xor(sd, off, 64);
      if (lr == 0) redD[wt2][wm + mt * 16 + lq * 4 + j] = sd;
    }
  __syncthreads();
  if (u < 128){
    int sg = b * 2048 + sb * 128 + u;
    Mp[tb * 16384 + sg] = fmaxf(fmaxf(redM[0][u], redM[1][u]),
                                fmaxf(redM[2][u], redM[3][u]));
    Dp[tb * 16384 + sg] = redD[0][u] + redD[1][u] + redD[2][u] + redD[3][u];
  }
}

// ---------------------------------------------------------------------------
// k_scm: merge the 8 per-tile partials -> SC16[ti][s] = exp2(M-m)/denom (f16).
// ---------------------------------------------------------------------------
__global__ __launch_bounds__(256) void k_scm(const float* __restrict__ Mp,
                                             const float* __restrict__ Dp,
                                             f16* __restrict__ SC16){
  int i = blockIdx.x * 256 + threadIdx.x;  // (b,s) flat, 16384
  float mv[8];
  float m = -1e30f;
#pragma unroll
  for (int ti = 0; ti < 8; ++ti){
    mv[ti] = Mp[ti * 16384 + i];
    m = fmaxf(m, mv[ti]);
  }
  float d = 0.f;
#pragma unroll
  for (int ti = 0; ti < 8; ++ti)
    d += Dp[ti * 16384 + i] * fexp2(mv[ti] - m);
  float rd = 1.0f / d;
#pragma unroll
  for (int ti = 0; ti < 8; ++ti)
    SC16[ti * 16384 + i] = (f16)(fexp2(mv[ti] - m) * rd);
}

// ---------------------------------------------------------------------------
// k_pass2p (v3): pure GEMM over K=s=2048, retiled for occupancy.
// Block = (b, tb 16 x 128t, hb 8 x 64h), grid 1024 -> 4 blocks/CU.
// BK=64 single-buffered: A (V^T 64h) 8KB + B (P' 128t) 16KB + scl 4KB =
// 28KB LDS. 4 waves, wave tile 32t x 64h (acc[4][2], 16 MFMA/chunk).
// Scale in registers: s = c*64 + es*32 + lq*8 + e. Stats: ti = tb>>1.
// ---------------------------------------------------------------------------
__global__ __launch_bounds__(256, 4) void k_pass2p(const f16* __restrict__ Pp,
                                                   const f16* __restrict__ VT,
                                                   const f16* __restrict__ SC16,
                                                   float* __restrict__ out){
  const int gid = blockIdx.x;
  const int b = gid & 7;
  const int tb = (gid >> 3) & 15;
  const int hb = gid >> 7;              // 0..7, 64-wide h tiles
  const int ti = tb >> 1;
  const int u = threadIdx.x;
  const int w = u >> 6, l = u & 63, lr = l & 15, lq = l >> 4;
  const int sx8 = (l & 7) ^ (l >> 3), hi8 = l >> 3;

  __shared__ __align__(16) f16 Abuf[64 * 64];   // V^T h-rows, 8KB
  __shared__ __align__(16) f16 Bbuf[128 * 64];  // P' t-rows, 16KB
  __shared__ __align__(16) f16 scl[2048];       // 4KB, sc row for this ti

  { // stage scale row (one f16x8 per thread)
    f16x8 v = *(const f16x8*)&SC16[(size_t)ti * 16384 + b * 2048 + u * 8];
    *(f16x8*)&scl[u * 8] = v;
  }
  f32x4 acc[4][2] = {};  // [ht][nt]
  const f16* sa0 = VT + ((size_t)(b * 512 + hb * 64) * 2048);
  const f16* sb0 = Pp + ((size_t)(b * 2048 + tb * 128) * 2048);
  for (int c = 0; c < 32; ++c){
    { // stage chunk c: A 8 slots (2/wave), B 16 slots (4/wave)
      const f16* sa = sa0 + c * 64;
      const f16* sb_ = sb0 + c * 64;
#pragma unroll
      for (int k = 0; k < 2; ++k){
        int i = w * 2 + k;
        int row = i * 8 + hi8;       // 0..63
        gld16((char*)Abuf + i * 1024, sa + (size_t)row * 2048 + sx8 * 8);
      }
#pragma unroll
      for (int k = 0; k < 4; ++k){
        int i = w * 4 + k;
        int row = i * 8 + hi8;       // 0..127
        gld16((char*)Bbuf + i * 1024, sb_ + (size_t)row * 2048 + sx8 * 8);
      }
    }
    __syncthreads();   // staged data (+ scl on c=0) visible
#pragma unroll
    for (int es = 0; es < 2; ++es){
      f16x8 sclv = *(const f16x8*)&scl[c * 64 + es * 32 + lq * 8]; // broadcast
      f16x8 af[4], bf[2];
#pragma unroll
      for (int ht = 0; ht < 4; ++ht){
        int row = ht * 16 + lr;      // h within 64
        af[ht] = *(const f16x8*)((const char*)Abuf + row * 128 + (((es * 4 + lq) ^ (row & 7)) << 4));
      }
#pragma unroll
      for (int nt = 0; nt < 2; ++nt){
        int row = w * 32 + nt * 16 + lr;  // t within 128
        f16x8 p = *(const f16x8*)((const char*)Bbuf + row * 128 + (((es * 4 + lq) ^ (row & 7)) << 4));
        bf[nt] = p * sclv;
      }
#pragma unroll
      for (int ht = 0; ht < 4; ++ht)
#pragma unroll
        for (int nt = 0; nt < 2; ++nt)
          acc[ht][nt] = mfma_f16(af[ht], bf[nt], acc[ht][nt]);
    }
    __syncthreads();   // all reads done before next chunk overwrites
  }
  // epilogue: h = hb*64 + ht*16 + lq*4 (+j), t = tb*128 + w*32 + nt*16 + lr
#pragma unroll
  for (int ht = 0; ht < 4; ++ht)
#pragma unroll
    for (int nt = 0; nt < 2; ++nt){
      int t = tb * 128 + w * 32 + nt * 16 + lr;
      int h = hb * 64 + ht * 16 + lq * 4;
      float4 v;
      v.x = acc[ht][nt][0]; v.y = acc[ht][nt][1];
      v.z = acc[ht][nt][2]; v.w = acc[ht][nt][3];
      *(float4*)&out[(size_t)(b * 2048 + t) * 512 + h] = v;
    }
}

// ---------------------------------------------------------------------------
extern "C" void kernel_launch(void* const* d_in, const int* in_sizes, int n_in,
                              void* d_out, int out_size, void* d_ws, size_t ws_size,
                              hipStream_t stream){
  (void)in_sizes; (void)n_in; (void)out_size; (void)ws_size;
  const float* tokens = (const float*)d_in[0];
  const float* Wq = (const float*)d_in[1];
  const float* Wk = (const float*)d_in[2];
  const float* Wv = (const float*)d_in[3];
  char* ws = (char*)d_ws;
  f16*    T16 = (f16*)(ws);                        // [0, 16M)
  f16*    QG  = (f16*)(ws + (16u << 20));          // [16M, 32M)
  f16*    VT  = (f16*)(ws + (32u << 20));          // [32M, 48M)
  f16*    B16 = (f16*)(ws + (48u << 20));          // [48M, 49M)
  f16*    SC16= (f16*)(ws + (50u << 20));          // [50M, 50.25M)
  float*  Mp  = (float*)(ws + (51u << 20));        // [51M, 51.5M)
  float*  Dp  = (float*)(ws + (52u << 20));        // [52M, 52.5M)
  f16*    Pp  = (f16*)(ws + (54u << 20));          // [54M, 118M)
  float* out = (float*)d_out;

  k_prep_g <<<dim3(16, 16), dim3(256), 0, stream>>>(Wq, Wk, B16);
  k_prep_wv<<<dim3(8, 8),   dim3(256), 0, stream>>>(Wv, B16);
  k_cast   <<<dim3(4096),   dim3(256), 0, stream>>>(tokens, T16);
  k_gemm   <<<dim3(128, 8), dim3(256), 0, stream>>>(T16, B16, QG, VT);
  k_pass1p <<<dim3(1024),   dim3(512), 0, stream>>>(T16, QG, Pp, Mp, Dp);
  k_scm    <<<dim3(64),     dim3(256), 0, stream>>>(Mp, Dp, SC16);
  k_pass2p <<<dim3(1024),   dim3(256), 0, stream>>>(Pp, VT, SC16, out);
}

// Round 19
// 161.175 us; speedup vs baseline: 1.2333x; 1.2333x over previous
//
#include <hip/hip_runtime.h>

typedef _Float16 f16;
typedef _Float16 f16x8 __attribute__((ext_vector_type(8)));
typedef _Float16 f16x4 __attribute__((ext_vector_type(4)));
typedef float   f32x4 __attribute__((ext_vector_type(4)));

#define LOG2E 1.44269504088896340736f

__device__ __forceinline__ f32x4 mfma_f16(f16x8 a, f16x8 b, f32x4 c){
  return __builtin_amdgcn_mfma_f32_16x16x32_f16(a, b, c, 0, 0, 0);
}
__device__ __forceinline__ float fexp2(float x){ return __builtin_amdgcn_exp2f(x); }

// global -> LDS direct DMA, 16B per lane. lds must be wave-uniform base;
// HW writes base + lane*16. Source address is per-lane (pre-swizzled).
__device__ __forceinline__ void gld16(void* lds, const void* g){
  __builtin_amdgcn_global_load_lds(
      (const __attribute__((address_space(1))) unsigned int*)g,
      (__attribute__((address_space(3))) unsigned int*)lds,
      16, 0, 0);
}

// BK=64 swizzle (128B rows): pos holds k-word (pos ^ (row&7));
//   staging XOR (l&7)^(l>>3); validated r3-r18 (0 conflicts).
// LESSONS: (r12) launch_bounds min-waves too high -> VGPR cap -> spill.
//          (r9/r15/r18) ALL pipelining grafts lose to single-buf BK=64 +
//          max blocks/CU for this 2-barrier class (occupancy + 128B-line
//          fetch granularity dominate). (r16) setprio null. (r17) pass2p
//          retile null. This file = r14 config, session best (161.3us).

// ---------------------------------------------------------------------------
// k_prep_g: B16[n][e] = sum_x Wk[n][x]*Wq[e][x]  (= (Wq Wk^T)^T), n<512.
// ---------------------------------------------------------------------------
__global__ __launch_bounds__(256) void k_prep_g(const float* __restrict__ Wq,
                                                const float* __restrict__ Wk,
                                                f16* __restrict__ B16){
  __shared__ float ak[32][36];
  __shared__ float aq[32][36];
  const int n0 = blockIdx.y * 32, e0 = blockIdx.x * 32;
  const int u = threadIdx.x;
  const int ty = u >> 4, tx = u & 15;
  float acc[2][2] = {};
  for (int x0 = 0; x0 < 512; x0 += 32){
    __syncthreads();
    {
      int r = u >> 3, c4 = (u & 7) * 4;
      *(float4*)&ak[r][c4] = *(const float4*)&Wk[(n0 + r) * 512 + x0 + c4];
      *(float4*)&aq[r][c4] = *(const float4*)&Wq[(e0 + r) * 512 + x0 + c4];
    }
    __syncthreads();
#pragma unroll 8
    for (int x = 0; x < 32; ++x){
      float k0 = ak[ty * 2 + 0][x], k1 = ak[ty * 2 + 1][x];
      float q0 = aq[tx * 2 + 0][x], q1 = aq[tx * 2 + 1][x];
      acc[0][0] += k0 * q0; acc[0][1] += k0 * q1;
      acc[1][0] += k1 * q0; acc[1][1] += k1 * q1;
    }
  }
#pragma unroll
  for (int i = 0; i < 2; ++i)
#pragma unroll
    for (int j = 0; j < 2; ++j)
      B16[(size_t)(n0 + ty * 2 + i) * 512 + e0 + tx * 2 + j] = (f16)acc[i][j];
}

// ---------------------------------------------------------------------------
// k_prep_wv: B16[512+d][e] = Wv[e][d]  (transpose + fp16 cast)
// ---------------------------------------------------------------------------
__global__ __launch_bounds__(256) void k_prep_wv(const float* __restrict__ Wv,
                                                 f16* __restrict__ B16){
  __shared__ float t[64][72];
  const int e0 = blockIdx.x * 64, h0 = blockIdx.y * 64;
  const int u = threadIdx.x;
#pragma unroll
  for (int k = 0; k < 4; ++k){
    int idx = u + k * 256; int r = idx >> 4, c4 = (idx & 15) * 4;
    *(float4*)&t[r][c4] = *(const float4*)&Wv[(e0 + r) * 512 + h0 + c4];
  }
  __syncthreads();
#pragma unroll
  for (int k = 0; k < 4; ++k){
    int idx = u + k * 256; int j = idx >> 4, i4 = (idx & 15) * 4;
#pragma unroll
    for (int c = 0; c < 4; ++c)
      B16[(size_t)(512 + h0 + j) * 512 + e0 + i4 + c] = (f16)t[i4 + c][j];
  }
}

// ---------------------------------------------------------------------------
// k_cast: tokens fp32 -> fp16, 8/thread.
// ---------------------------------------------------------------------------
__global__ __launch_bounds__(256) void k_cast(const float* __restrict__ tok,
                                              f16* __restrict__ T16){
  int i = blockIdx.x * 256 + threadIdx.x;
  const float4* p = (const float4*)tok + (size_t)i * 2;
  float4 a = p[0], b = p[1];
  f16x8 h;
  h[0] = (f16)a.x; h[1] = (f16)a.y; h[2] = (f16)a.z; h[3] = (f16)a.w;
  h[4] = (f16)b.x; h[5] = (f16)b.y; h[6] = (f16)b.z; h[7] = (f16)b.w;
  *((f16x8*)T16 + i) = h;
}

// ---------------------------------------------------------------------------
// k_gemm: C[t][n] = sum_e T16[t][e]*B16[n][e]; n<512 -> QG[t][n],
// n>=512 -> VT[b][d][s]. 128x128 tile, BK=64 single-buffered, 32KB LDS ->
// 4 blocks/CU (r14-validated).
// ---------------------------------------------------------------------------
__global__ __launch_bounds__(256, 4) void k_gemm(const f16* __restrict__ T16,
                                                 const f16* __restrict__ B16,
                                                 f16* __restrict__ QG,
                                                 f16* __restrict__ VT){
  __shared__ __align__(16) f16 Abuf[128 * 64];  // 16KB
  __shared__ __align__(16) f16 Bbuf[128 * 64];  // 16KB
  const int tb = blockIdx.x, nb = blockIdx.y;
  const int u = threadIdx.x;
  const int w = u >> 6, l = u & 63, lr = l & 15, lq = l >> 4;
  const int sx8 = (l & 7) ^ (l >> 3), hi8 = l >> 3;
  const int wm = (w & 1) * 64, wn = (w >> 1) * 64;
  f32x4 acc[4][4] = {};
  const f16* sa0 = T16 + (size_t)tb * 128 * 512;
  const f16* sb0 = B16 + (size_t)nb * 128 * 512;
  for (int c = 0; c < 8; ++c){
    {
      const f16* sa = sa0 + c * 64;
      const f16* sb_ = sb0 + c * 64;
#pragma unroll
      for (int k = 0; k < 4; ++k){
        int i = w * 4 + k;
        int row = i * 8 + hi8;
        gld16((char*)Abuf + i * 1024, sa  + (size_t)row * 512 + sx8 * 8);
        gld16((char*)Bbuf + i * 1024, sb_ + (size_t)row * 512 + sx8 * 8);
      }
    }
    __syncthreads();
#pragma unroll
    for (int es = 0; es < 2; ++es){
      f16x8 af[4], bf[4];
#pragma unroll
      for (int mt = 0; mt < 4; ++mt){
        int row = wm + mt * 16 + lr;
        af[mt] = *(const f16x8*)((const char*)Abuf + row * 128 + (((es * 4 + lq) ^ (row & 7)) << 4));
      }
#pragma unroll
      for (int nt = 0; nt < 4; ++nt){
        int row = wn + nt * 16 + lr;
        bf[nt] = *(const f16x8*)((const char*)Bbuf + row * 128 + (((es * 4 + lq) ^ (row & 7)) << 4));
      }
#pragma unroll
      for (int mt = 0; mt < 4; ++mt)
#pragma unroll
        for (int nt = 0; nt < 4; ++nt)
          acc[mt][nt] = mfma_f16(af[mt], bf[nt], acc[mt][nt]);
    }
    __syncthreads();
  }
  if (nb < 4){
#pragma unroll
    for (int mt = 0; mt < 4; ++mt)
#pragma unroll
      for (int nt = 0; nt < 4; ++nt){
        int n = nb * 128 + wn + nt * 16 + lr;
        int r0 = tb * 128 + wm + mt * 16 + lq * 4;
#pragma unroll
        for (int j = 0; j < 4; ++j)
          QG[(size_t)(r0 + j) * 512 + n] = (f16)acc[mt][nt][j];
      }
  } else {
#pragma unroll
    for (int mt = 0; mt < 4; ++mt)
#pragma unroll
      for (int nt = 0; nt < 4; ++nt){
        int h = (nb - 4) * 128 + wn + nt * 16 + lr;
        int r0 = tb * 128 + wm + mt * 16 + lq * 4;
        int bq = r0 >> 11, s = r0 & 2047;
        f16x4 hv;
#pragma unroll
        for (int j = 0; j < 4; ++j) hv[j] = (f16)acc[mt][nt][j];
        *(f16x4*)&VT[(size_t)(bq * 512 + h) * 2048 + s] = hv;
      }
  }
}

// ---------------------------------------------------------------------------
// k_pass1p: S-GEMM 128s x 256t tile, 512 threads (8 waves, wave 64x64),
// BK=64 single-buffered (32 MFMA/wave/chunk). LDS 52KB -> 3 blocks/CU.
// launch_bounds (512,2). Block = (b, sb 16, tb 8), grid 1024.
// r14-validated at 57.5us.
// ---------------------------------------------------------------------------
__global__ __launch_bounds__(512, 2) void k_pass1p(const f16* __restrict__ T16,
                                                   const f16* __restrict__ QG,
                                                   f16* __restrict__ Pp,
                                                   float* __restrict__ Mp,
                                                   float* __restrict__ Dp){
  const int gid = blockIdx.x;
  const int b = gid & 7;
  const int sb = (gid >> 3) & 15;
  const int tb = gid >> 7;              // 0..7, 256-wide t tiles
  const int u = threadIdx.x;
  const int w = u >> 6, l = u & 63, lr = l & 15, lq = l >> 4;
  const int sx8 = (l & 7) ^ (l >> 3), hi8 = l >> 3;
  const int ws2 = w & 1, wt2 = w >> 1;  // s half, t quarter
  const int wm = ws2 * 64, wn = wt2 * 64;

  __shared__ __align__(16) f16 Abuf[128 * 64];  // T16 s-rows, 16KB
  __shared__ __align__(16) f16 Bbuf[256 * 64];  // QG  t-rows, 32KB
  __shared__ float redM[4][128];
  __shared__ float redD[4][128];

  f32x4 acc[4][4] = {};
  const f16* sa0 = T16 + ((size_t)(b * 2048 + sb * 128) * 512);
  const f16* sb0 = QG + ((size_t)(b * 2048 + tb * 256) * 512);
  for (int c = 0; c < 8; ++c){
    { // stage chunk c: A 16 slots (2/wave), B 32 slots (4/wave)
      const f16* sa = sa0 + c * 64;
      const f16* sb_ = sb0 + c * 64;
#pragma unroll
      for (int k = 0; k < 2; ++k){
        int i = w * 2 + k;
        int row = i * 8 + hi8;       // 0..127
        gld16((char*)Abuf + i * 1024, sa + (size_t)row * 512 + sx8 * 8);
      }
#pragma unroll
      for (int k = 0; k < 4; ++k){
        int i = w * 4 + k;
        int row = i * 8 + hi8;       // 0..255
        gld16((char*)Bbuf + i * 1024, sb_ + (size_t)row * 512 + sx8 * 8);
      }
    }
    __syncthreads();   // staged data visible
#pragma unroll
    for (int es = 0; es < 2; ++es){
      f16x8 af[4], bf[4];
#pragma unroll
      for (int mt = 0; mt < 4; ++mt){
        int row = wm + mt * 16 + lr;
        af[mt] = *(const f16x8*)((const char*)Abuf + row * 128 + (((es * 4 + lq) ^ (row & 7)) << 4));
      }
#pragma unroll
      for (int nt = 0; nt < 4; ++nt){
        int row = wn + nt * 16 + lr;
        bf[nt] = *(const f16x8*)((const char*)Bbuf + row * 128 + (((es * 4 + lq) ^ (row & 7)) << 4));
      }
#pragma unroll
      for (int mt = 0; mt < 4; ++mt)
#pragma unroll
        for (int nt = 0; nt < 4; ++nt)
          acc[mt][nt] = mfma_f16(af[mt], bf[nt], acc[mt][nt]);
    }
    __syncthreads();   // all reads done before next chunk overwrites
  }
  // ---- epilogue: x = S*log2e; col max over the block's 256 t ----
#pragma unroll
  for (int mt = 0; mt < 4; ++mt)
#pragma unroll
    for (int nt = 0; nt < 4; ++nt)
#pragma unroll
      for (int j = 0; j < 4; ++j)
        acc[mt][nt][j] *= LOG2E;
#pragma unroll
  for (int mt = 0; mt < 4; ++mt)
#pragma unroll
    for (int j = 0; j < 4; ++j){
      float m2 = fmaxf(fmaxf(acc[mt][0][j], acc[mt][1][j]),
                       fmaxf(acc[mt][2][j], acc[mt][3][j]));
#pragma unroll
      for (int off = 1; off <= 8; off <<= 1)
        m2 = fmaxf(m2, __shfl_xor(m2, off, 64));
      if (lr == 0) redM[wt2][wm + mt * 16 + lq * 4 + j] = m2;
    }
  __syncthreads();
  float M[4][4];
#pragma unroll
  for (int mt = 0; mt < 4; ++mt)
#pragma unroll
    for (int j = 0; j < 4; ++j){
      int idx = wm + mt * 16 + lq * 4 + j;
      M[mt][j] = fmaxf(fmaxf(redM[0][idx], redM[1][idx]),
                       fmaxf(redM[2][idx], redM[3][idx]));
    }
  // ---- P' = exp2(x - M), store fp16, col sums ----
#pragma unroll
  for (int mt = 0; mt < 4; ++mt)
#pragma unroll
    for (int nt = 0; nt < 4; ++nt){
      int t = tb * 256 + wn + nt * 16 + lr;
      f16x4 h4;
#pragma unroll
      for (int j = 0; j < 4; ++j){
        float p = fexp2(acc[mt][nt][j] - M[mt][j]);
        acc[mt][nt][j] = p;
        h4[j] = (f16)p;
      }
      *(f16x4*)&Pp[(size_t)(b * 2048 + t) * 2048 + sb * 128 + wm + mt * 16 + lq * 4] = h4;
    }
#pragma unroll
  for (int mt = 0; mt < 4; ++mt)
#pragma unroll
    for (int j = 0; j < 4; ++j){
      float sd = acc[mt][0][j] + acc[mt][1][j] + acc[mt][2][j] + acc[mt][3][j];
#pragma unroll
      for (int off = 1; off <= 8; off <<= 1)
        sd += __shfl_xor(sd, off, 64);
      if (lr == 0) redD[wt2][wm + mt * 16 + lq * 4 + j] = sd;
    }
  __syncthreads();
  if (u < 128){
    int sg = b * 2048 + sb * 128 + u;
    Mp[tb * 16384 + sg] = fmaxf(fmaxf(redM[0][u], redM[1][u]),
                                fmaxf(redM[2][u], redM[3][u]));
    Dp[tb * 16384 + sg] = redD[0][u] + redD[1][u] + redD[2][u] + redD[3][u];
  }
}

// ---------------------------------------------------------------------------
// k_scm: merge the 8 per-tile partials -> SC16[ti][s] = exp2(M-m)/denom (f16).
// ---------------------------------------------------------------------------
__global__ __launch_bounds__(256) void k_scm(const float* __restrict__ Mp,
                                             const float* __restrict__ Dp,
                                             f16* __restrict__ SC16){
  int i = blockIdx.x * 256 + threadIdx.x;  // (b,s) flat, 16384
  float mv[8];
  float m = -1e30f;
#pragma unroll
  for (int ti = 0; ti < 8; ++ti){
    mv[ti] = Mp[ti * 16384 + i];
    m = fmaxf(m, mv[ti]);
  }
  float d = 0.f;
#pragma unroll
  for (int ti = 0; ti < 8; ++ti)
    d += Dp[ti * 16384 + i] * fexp2(mv[ti] - m);
  float rd = 1.0f / d;
#pragma unroll
  for (int ti = 0; ti < 8; ++ti)
    SC16[ti * 16384 + i] = (f16)(fexp2(mv[ti] - m) * rd);
}

// ---------------------------------------------------------------------------
// k_pass2p: pure GEMM over K=s=2048. Block = (b, tb 16, hb 4), grid 512
// (grid-limited to 2 blocks/CU -> BK=64: 32 K-steps, 32 MFMA/wave/step,
// 68KB LDS, dbuf). row&7 swizzle. Scale in registers:
// s = c*64+es*32+lq*8+e. Stats tiles are 256-wide -> ti = tb>>1.
// ---------------------------------------------------------------------------
__global__ __launch_bounds__(256, 2) void k_pass2p(const f16* __restrict__ Pp,
                                                   const f16* __restrict__ VT,
                                                   const f16* __restrict__ SC16,
                                                   float* __restrict__ out){
  const int gid = blockIdx.x;
  const int b = gid & 7;
  const int tb = (gid >> 3) & 15;
  const int hb = gid >> 7;
  const int ti = tb >> 1;
  const int u = threadIdx.x;
  const int w = u >> 6, l = u & 63, lr = l & 15, lq = l >> 4;
  const int sx8 = (l & 7) ^ (l >> 3), hi8 = l >> 3;
  const int wm = (w & 1) * 64, wn = (w >> 1) * 64;  // h, t within tile

  __shared__ __align__(16) f16 Abuf[2][128 * 64];  // V^T h-rows, 2*16KB
  __shared__ __align__(16) f16 Bbuf[2][128 * 64];  // P' t-rows, 2*16KB
  __shared__ __align__(16) f16 scl[2048];          // 4KB, sc row for this tb

  { // stage scale row (one f16x8 per thread)
    f16x8 v = *(const f16x8*)&SC16[(size_t)ti * 16384 + b * 2048 + u * 8];
    *(f16x8*)&scl[u * 8] = v;
  }
  f32x4 acc[4][4] = {};
  auto stage = [&](int c, int buf){
    const f16* sa = VT + ((size_t)(b * 512 + hb * 128) * 2048 + c * 64);
    const f16* sb_ = Pp + ((size_t)(b * 2048 + tb * 128) * 2048 + c * 64);
#pragma unroll
    for (int k = 0; k < 4; ++k){
      int i = w * 4 + k;            // 0..15
      int row = i * 8 + hi8;        // 0..127
      gld16((char*)&Abuf[buf][0] + i * 1024, sa  + (size_t)row * 2048 + sx8 * 8);
      gld16((char*)&Bbuf[buf][0] + i * 1024, sb_ + (size_t)row * 2048 + sx8 * 8);
    }
  };
  stage(0, 0);
  for (int c = 0; c < 32; ++c){
    __syncthreads();   // drains gld16 (vmcnt) and scl ds_write (lgkmcnt) on c=0
    if (c < 31) stage(c + 1, (c + 1) & 1);
    const f16* A = &Abuf[c & 1][0];
    const f16* B = &Bbuf[c & 1][0];
#pragma unroll
    for (int es = 0; es < 2; ++es){
      f16x8 sclv = *(const f16x8*)&scl[c * 64 + es * 32 + lq * 8]; // broadcast
      f16x8 af[4], bf[4];
#pragma unroll
      for (int mt = 0; mt < 4; ++mt){
        int row = wm + mt * 16 + lr;
        af[mt] = *(const f16x8*)((const char*)A + row * 128 + (((es * 4 + lq) ^ (row & 7)) << 4));
      }
#pragma unroll
      for (int nt = 0; nt < 4; ++nt){
        int row = wn + nt * 16 + lr;
        f16x8 p = *(const f16x8*)((const char*)B + row * 128 + (((es * 4 + lq) ^ (row & 7)) << 4));
        bf[nt] = p * sclv;
      }
#pragma unroll
      for (int mt = 0; mt < 4; ++mt)
#pragma unroll
        for (int nt = 0; nt < 4; ++nt)
          acc[mt][nt] = mfma_f16(af[mt], bf[nt], acc[mt][nt]);
    }
  }
  // epilogue: h = hb*128 + wm + mt*16 + lq*4 (+j), t = tb*128 + wn + nt*16 + lr
#pragma unroll
  for (int mt = 0; mt < 4; ++mt)
#pragma unroll
    for (int nt = 0; nt < 4; ++nt){
      int t = tb * 128 + wn + nt * 16 + lr;
      int h = hb * 128 + wm + mt * 16 + lq * 4;
      float4 v;
      v.x = acc[mt][nt][0]; v.y = acc[mt][nt][1];
      v.z = acc[mt][nt][2]; v.w = acc[mt][nt][3];
      *(float4*)&out[(size_t)(b * 2048 + t) * 512 + h] = v;
    }
}

// ---------------------------------------------------------------------------
extern "C" void kernel_launch(void* const* d_in, const int* in_sizes, int n_in,
                              void* d_out, int out_size, void* d_ws, size_t ws_size,
                              hipStream_t stream){
  (void)in_sizes; (void)n_in; (void)out_size; (void)ws_size;
  const float* tokens = (const float*)d_in[0];
  const float* Wq = (const float*)d_in[1];
  const float* Wk = (const float*)d_in[2];
  const float* Wv = (const float*)d_in[3];
  char* ws = (char*)d_ws;
  f16*    T16 = (f16*)(ws);                        // [0, 16M)
  f16*    QG  = (f16*)(ws + (16u << 20));          // [16M, 32M)
  f16*    VT  = (f16*)(ws + (32u << 20));          // [32M, 48M)
  f16*    B16 = (f16*)(ws + (48u << 20));          // [48M, 49M)
  f16*    SC16= (f16*)(ws + (50u << 20));          // [50M, 50.25M)
  float*  Mp  = (float*)(ws + (51u << 20));        // [51M, 51.5M)
  float*  Dp  = (float*)(ws + (52u << 20));        // [52M, 52.5M)
  f16*    Pp  = (f16*)(ws + (54u << 20));          // [54M, 118M)
  float* out = (float*)d_out;

  k_prep_g <<<dim3(16, 16), dim3(256), 0, stream>>>(Wq, Wk, B16);
  k_prep_wv<<<dim3(8, 8),   dim3(256), 0, stream>>>(Wv, B16);
  k_cast   <<<dim3(4096),   dim3(256), 0, stream>>>(tokens, T16);
  k_gemm   <<<dim3(128, 8), dim3(256), 0, stream>>>(T16, B16, QG, VT);
  k_pass1p <<<dim3(1024),   dim3(512), 0, stream>>>(T16, QG, Pp, Mp, Dp);
  k_scm    <<<dim3(64),     dim3(256), 0, stream>>>(Mp, Dp, SC16);
  k_pass2p <<<dim3(512),    dim3(256), 0, stream>>>(Pp, VT, SC16, out);
}